// Round 18
// baseline (58.909 us; speedup 1.0000x reference)
//
#include <hip/hip_runtime.h>
#include <hip/hip_fp16.h>
#include <math.h>

#define TT 16
#define HH 64
#define WW 64
#define CC 128
#define PI2 6.283185307179586f

// XOR digit swizzle: row r = hi*8+lo -> hi*8 + (lo^hi). Keeps stride-8 and
// block-8 row accesses <=2-way banked in the narrow [.,64][4] tiles.
#define LROW(r) (((r) & 0x38) | ((((r) >> 3) ^ (r)) & 7))

// 2-wide float vector: complex (re,im). Vector +,-,* lower to v_pk_*_f32.
typedef float vf2 __attribute__((ext_vector_type(2)));
#define MKV(a,b) (vf2){(float)(a), (float)(b)}

__device__ __forceinline__ vf2 vswap(vf2 a) { return __builtin_shufflevector(a, a, 1, 0); }
// rot<SGN>(a) = SGN*i*a = (-SGN*a.y, SGN*a.x)
template<int SGN>
__device__ __forceinline__ vf2 vrot(vf2 a) { return vswap(a) * MKV(-SGN, SGN); }
__device__ __forceinline__ vf2 cmul(vf2 a, vf2 b) {
    return MKV(a.x, a.x) * b + MKV(-a.y, a.y) * vswap(b);
}
__device__ __forceinline__ vf2 cmac(vf2 acc, vf2 a, vf2 b) {
    return acc + cmul(a, b);
}
__device__ __forceinline__ vf2 csq(vf2 a) { return cmul(a, a); }

// ---------------- radix butterflies (packed) ----------------
template<int SGN>
__device__ __forceinline__ void dft4(vf2 b0, vf2 b1, vf2 b2, vf2 b3,
                                     vf2& y0, vf2& y1, vf2& y2, vf2& y3) {
    vf2 e0 = b0 + b2, e1 = b0 - b2;
    vf2 o0 = b1 + b3, o1 = b1 - b3;
    y0 = e0 + o0; y2 = e0 - o0;
    vf2 r = vrot<SGN>(o1);
    y1 = e1 + r; y3 = e1 - r;
}

template<int SGN>
__device__ __forceinline__ void dft8(const vf2* a, vf2* X) {
    const float C = 0.70710678118654752f;
    vf2 E0,E1,E2,E3,O0,O1,O2,O3;
    dft4<SGN>(a[0],a[2],a[4],a[6], E0,E1,E2,E3);
    dft4<SGN>(a[1],a[3],a[5],a[7], O0,O1,O2,O3);
    vf2 T1 = (O1 + vrot<SGN>(O1)) * MKV(C, C);
    vf2 T2 = vrot<SGN>(O2);
    vf2 T3 = (vrot<SGN>(O3) - O3) * MKV(C, C);
    X[0]=E0+O0; X[4]=E0-O0;
    X[1]=E1+T1; X[5]=E1-T1;
    X[2]=E2+T2; X[6]=E2-T2;
    X[3]=E3+T3; X[7]=E3-T3;
}

template<int SGN>
__device__ __forceinline__ void dft16(const vf2* v, vf2* X) {
    const float ct[10] = {1.f, 0.92387953251f, 0.70710678119f, 0.38268343236f, 0.f,
                          0.f, -0.70710678119f, 0.f, 0.f, -0.92387953251f};
    const float st[10] = {0.f, 0.38268343236f, 0.70710678119f, 0.92387953251f, 1.f,
                          0.f, 0.70710678119f, 0.f, 0.f, -0.38268343236f};
    vf2 Z[16];
    #pragma unroll
    for (int h0 = 0; h0 < 4; ++h0) {
        vf2 y0,y1,y2,y3;
        dft4<SGN>(v[h0], v[4+h0], v[8+h0], v[12+h0], y0,y1,y2,y3);
        vf2 ys[4] = {y0,y1,y2,y3};
        #pragma unroll
        for (int k0 = 0; k0 < 4; ++k0) {
            int m = h0 * k0;
            Z[k0*4 + h0] = cmul(ys[k0], MKV(ct[m], (float)SGN * st[m]));
        }
    }
    #pragma unroll
    for (int k0 = 0; k0 < 4; ++k0) {
        vf2 y0,y1,y2,y3;
        dft4<SGN>(Z[k0*4+0], Z[k0*4+1], Z[k0*4+2], Z[k0*4+3], y0,y1,y2,y3);
        X[k0] = y0; X[k0+4] = y1; X[k0+8] = y2; X[k0+12] = y3;
    }
}

// Z layout (uint4 = 4 half2 = 4 channels): index ((om*32 + cc)*16 + t)*64 + h.
// Each pmid block owns one contiguous 16 KB chunk (om,cc).

// ======== fused pass A: blocks 0..1023 = p1 (paired real W-FFT), 1024..1221 = k_prep ====
__global__ __launch_bounds__(256) void pA(const float* __restrict__ x,
                                          uint4* __restrict__ Z,
                                          const float* __restrict__ Ak,
                                          const float* __restrict__ Bk,
                                          __half2* __restrict__ Ahw,
                                          __half2* __restrict__ Bhw) {
    __shared__ __align__(16) char smem[32768];
    int bid = blockIdx.x;
    int tid = threadIdx.x;
    if (bid < 1024) {
        float (*zsre)[64][32] = (float(*)[64][32])smem;             // 16 KB
        float (*zsim)[64][32] = (float(*)[64][32])(smem + 16384);   // 16 KB
        float (*spre)[64][32] = (float(*)[64][32])smem;             // alias
        float (*spim)[64][32] = (float(*)[64][32])(smem + 16384);   // alias
        int cq = bid & 3, hq = (bid >> 2) & 15, t = bid >> 6;
        int c = tid & 31, s4 = tid >> 5;           // s4 in [0,8)
        float twc[8], tws[8];
        {
            float s1, c1; sincosf(-PI2 * s4 / 64.0f, &s1, &c1);
            twc[0] = 1.f; tws[0] = 0.f;
            #pragma unroll
            for (int k = 1; k < 8; ++k) {
                twc[k] = twc[k-1]*c1 - tws[k-1]*s1;
                tws[k] = twc[k-1]*s1 + tws[k-1]*c1;
            }
        }
        const float* xb = x + (size_t)(t*64 + hq*4) * 8192 + cq * 32 + c;
        // stage 1: packed complex input (plane 2p = re, plane 2p+1 = im), fp32 out
        #pragma unroll
        for (int p = 0; p < 2; ++p) {
            vf2 a[8], Y[8];
            #pragma unroll
            for (int h1 = 0; h1 < 8; ++h1) {
                size_t off = (size_t)(h1*8 + s4) * 128;
                a[h1] = MKV(xb[(size_t)(2*p) * 8192 + off],
                            xb[(size_t)(2*p+1) * 8192 + off]);
            }
            dft8<-1>(a, Y);
            #pragma unroll
            for (int k0 = 0; k0 < 8; ++k0) {
                int row = k0*8 + s4;
                vf2 z = cmul(Y[k0], MKV(twc[k0], tws[k0]));
                zsre[p][row][c] = z.x;
                zsim[p][row][c] = z.y;
            }
        }
        __syncthreads();                                      // B1
        // stage 2: read ALL zs inputs for both pairs, dft8 in registers
        vf2 X0[8], X1[8];
        {
            vf2 b[8];
            #pragma unroll
            for (int h0 = 0; h0 < 8; ++h0)
                b[h0] = MKV(zsre[0][s4*8 + h0][c], zsim[0][s4*8 + h0][c]);
            dft8<-1>(b, X0);
            #pragma unroll
            for (int h0 = 0; h0 < 8; ++h0)
                b[h0] = MKV(zsre[1][s4*8 + h0][c], zsim[1][s4*8 + h0][c]);
            dft8<-1>(b, X1);
        }
        __syncthreads();                                      // B2 (alias safe)
        #pragma unroll
        for (int k1 = 0; k1 < 8; ++k1) {
            int row = s4 + 8*k1;
            spre[0][row][c] = X0[k1].x; spim[0][row][c] = X0[k1].y;
            spre[1][row][c] = X1[k1].x; spim[1][row][c] = X1[k1].y;
        }
        __syncthreads();                                      // B3
        // unpack + dense write
        for (int i = tid; i < 528; i += 256) {                // p(2) x ccl(8) x om(33)
            int p = i & 1, ccl = (i >> 1) & 7, om = i >> 4;
            int mo = (64 - om) & 63;
            uint4 u1, u2;
            unsigned int* p1o = &u1.x;
            unsigned int* p2o = &u2.x;
            #pragma unroll
            for (int j = 0; j < 4; ++j) {
                int cb = ccl*4 + j;
                vf2 za = MKV(spre[p][om][cb], spim[p][om][cb]);
                vf2 zb = MKV(spre[p][mo][cb], spim[p][mo][cb]);
                float2 Xa = make_float2(0.5f*(za.x + zb.x), 0.5f*(za.y - zb.y));
                float2 Xb = make_float2(0.5f*(za.y + zb.y), 0.5f*(zb.x - za.x));
                __half2 h1v = __float22half2_rn(Xa);
                __half2 h2v = __float22half2_rn(Xb);
                p1o[j] = *(unsigned int*)&h1v;
                p2o[j] = *(unsigned int*)&h2v;
            }
            size_t base = ((size_t)(om*32 + cq*8 + ccl)*16 + t)*64 + hq*4;
            Z[base + 2*p]     = u1;
            Z[base + 2*p + 1] = u2;
        }
    } else {
        // ---------------- k_prep role (packed complex helpers) ----------------
        float (*Asl)[7][64] = (float(*)[7][64])smem;
        float (*Bsl)[7][64] = (float(*)[7][64])(smem + 12544);
        float2 (*Awl)[64]   = (float2(*)[64])(smem + 25088);
        float2 (*Bwl)[64]   = (float2(*)[64])(smem + 28672);
        float2* tw64        = (float2*)(smem + 32256);
        int kid = bid - 1024;
        int kt = kid / 66;
        int rem = kid % 66;
        int om = rem >> 1, chalf = rem & 1;
        int c0 = chalf * 64;
        for (int i = tid; i < 64; i += 256) {
            float s, cw; sincosf(-PI2 * i / 64.0f, &s, &cw);
            tw64[i] = make_float2(cw, s);
        }
        for (int i = tid; i < 49 * 64; i += 256) {
            int p = i >> 6, cl = i & 63;
            int kh = p / 7, kw = p % 7;
            int idx = (((c0 + cl) * 3 + kt) * 7 + kh) * 7 + kw;
            Asl[kh][kw][cl] = 0.9f * tanhf(Ak[idx]);
            Bsl[kh][kw][cl] = Bk[idx];
        }
        __syncthreads();
        for (int i = tid; i < 7 * 64; i += 256) {
            int kh = i >> 6, cl = i & 63;
            vf2 aA = MKV(0.f,0.f), aB = MKV(0.f,0.f);
            #pragma unroll
            for (int kw = 0; kw < 7; ++kw) {
                float2 tw = tw64[(om * (kw - 3)) & 63];
                vf2 twv = MKV(tw.x, tw.y);
                aA += MKV(Asl[kh][kw][cl], Asl[kh][kw][cl]) * twv;
                aB += MKV(Bsl[kh][kw][cl], Bsl[kh][kw][cl]) * twv;
            }
            Awl[kh][cl] = make_float2(aA.x, aA.y);
            Bwl[kh][cl] = make_float2(aB.x, aB.y);
        }
        __syncthreads();
        for (int i = tid; i < 64 * 64; i += 256) {
            int eta = i >> 6, cl = i & 63;
            vf2 aA = MKV(0.f,0.f), aB = MKV(0.f,0.f);
            #pragma unroll
            for (int kh = 0; kh < 7; ++kh) {
                float2 tw = tw64[(eta * (kh - 3)) & 63];
                vf2 twv = MKV(tw.x, tw.y);
                aA = cmac(aA, MKV(Awl[kh][cl].x, Awl[kh][cl].y), twv);
                aB = cmac(aB, MKV(Bwl[kh][cl].x, Bwl[kh][cl].y), twv);
            }
            int ep = ((eta & 7) << 3) | (eta >> 3);  // digit-swapped eta position
            int o = ((kt * 33 + om) * 64 + ep) * 128 + c0 + cl;
            Ahw[o] = __float22half2_rn(make_float2(aA.x, aA.y));
            Bhw[o] = __float22half2_rn(make_float2(aB.x, aB.y));
        }
    }
}

// ------- fused middle pass: fp32 SoA LDS, packed complex math -------
__global__ __launch_bounds__(256) void pmid(uint4* __restrict__ Z,
                                            const __half2* __restrict__ Ahw,
                                            const __half2* __restrict__ Bhw) {
    __shared__ float tre[16][64][4];      // 16 KB
    __shared__ float tim[16][64][4];      // 16 KB
    int l = (blockIdx.x & 7) * 132 + (blockIdx.x >> 3);   // XCD-chunked, bijective
    int om = l >> 5, cc = l & 31;
    int c0 = cc * 4;
    int tid = threadIdx.x;
    uint4* g = Z + (size_t)l * 1024;

    int d = tid & 7;
    float twc[8], tws[8];
    {
        float s1, c1; sincosf(-PI2 * d / 64.0f, &s1, &c1);
        twc[0] = 1.f; tws[0] = 0.f;
        #pragma unroll
        for (int k = 1; k < 8; ++k) {
            twc[k] = twc[k-1]*c1 - tws[k-1]*s1;
            tws[k] = twc[k-1]*s1 + tws[k-1]*c1;
        }
    }
    for (int i = tid; i < 1024; i += 256) {
        uint4 u = g[i];
        int t = i >> 6, h = i & 63;
        int pr = LROW(h);
        float2 v0 = __half22float2(*(__half2*)&u.x);
        float2 v1 = __half22float2(*(__half2*)&u.y);
        float2 v2 = __half22float2(*(__half2*)&u.z);
        float2 v3 = __half22float2(*(__half2*)&u.w);
        tre[t][pr][0] = v0.x; tim[t][pr][0] = v0.y;
        tre[t][pr][1] = v1.x; tim[t][pr][1] = v1.y;
        tre[t][pr][2] = v2.x; tim[t][pr][2] = v2.y;
        tre[t][pr][3] = v3.x; tim[t][pr][3] = v3.y;
    }
    __syncthreads();
    int cl = (tid >> 3) & 3, ts = tid >> 5;          // ts in [0,8)
    // H forward stage 1
    #pragma unroll
    for (int q = 0; q < 2; ++q) {
        int t = ts*2 + q;
        vf2 a[8], Y[8];
        #pragma unroll
        for (int h1 = 0; h1 < 8; ++h1) {
            int pr = LROW(h1*8 + d);
            a[h1] = MKV(tre[t][pr][cl], tim[t][pr][cl]);
        }
        dft8<-1>(a, Y);
        #pragma unroll
        for (int k0 = 0; k0 < 8; ++k0) {
            int pr = LROW(k0*8 + d);
            vf2 z = cmul(Y[k0], MKV(twc[k0], tws[k0]));
            tre[t][pr][cl] = z.x;
            tim[t][pr][cl] = z.y;
        }
    }
    __syncthreads();
    // H forward stage 2
    #pragma unroll
    for (int q = 0; q < 2; ++q) {
        int t = ts*2 + q;
        vf2 a[8], Y[8];
        #pragma unroll
        for (int h0 = 0; h0 < 8; ++h0) {
            int pr = LROW(d*8 + h0);
            a[h0] = MKV(tre[t][pr][cl], tim[t][pr][cl]);
        }
        dft8<-1>(a, Y);
        #pragma unroll
        for (int k1 = 0; k1 < 8; ++k1) {
            int pr = LROW(d*8 + k1);
            tre[t][pr][cl] = Y[k1].x; tim[t][pr][cl] = Y[k1].y;
        }
    }
    __syncthreads();
    // T phase
    {
        const float CT16[16] = {1.f, 0.9238795325f, 0.7071067812f, 0.3826834324f, 0.f,
                                -0.3826834324f, -0.7071067812f, -0.9238795325f, -1.f,
                                -0.9238795325f, -0.7071067812f, -0.3826834324f, 0.f,
                                0.3826834324f, 0.7071067812f, 0.9238795325f};
        const float ST16[16] = {0.f, 0.3826834324f, 0.7071067812f, 0.9238795325f, 1.f,
                                0.9238795325f, 0.7071067812f, 0.3826834324f, 0.f,
                                -0.3826834324f, -0.7071067812f, -0.9238795325f, -1.f,
                                -0.9238795325f, -0.7071067812f, -0.3826834324f};
        int cg = tid & 3, rT = tid >> 2;             // rT in [0,64)
        const int PKT = 33 * 64 * 128;
        int kb = (om * 64 + rT) * 128 + c0 + cg;
        float2 a0f = __half22float2(Ahw[kb]);
        float2 a1f = __half22float2(Ahw[kb + PKT]);
        float2 a2f = __half22float2(Ahw[kb + 2*PKT]);
        float2 b0f = __half22float2(Bhw[kb]);
        float2 b1f = __half22float2(Bhw[kb + PKT]);
        float2 b2f = __half22float2(Bhw[kb + 2*PKT]);
        vf2 A0 = MKV(a0f.x, a0f.y), A1 = MKV(a1f.x, a1f.y), A2 = MKV(a2f.x, a2f.y);
        vf2 B0 = MKV(b0f.x, b0f.y), B1 = MKV(b1f.x, b1f.y), B2 = MKV(b2f.x, b2f.y);
        int pr = LROW(rT);
        vf2 v[16], X[16];
        #pragma unroll
        for (int t = 0; t < 16; ++t) v[t] = MKV(tre[t][pr][cg], tim[t][pr][cg]);
        dft16<-1>(v, X);
        #pragma unroll
        for (int ta = 0; ta < 16; ++ta) {
            vf2 wv = MKV(CT16[ta], -ST16[ta]);
            vf2 wc = MKV(CT16[ta],  ST16[ta]);
            vf2 Af = cmac(cmac(A1, A0, wc), A2, wv);
            vf2 Bf = cmac(cmac(B1, B0, wc), B2, wv);
            // S = sum_{k=0}^{7} Af^k = (1+Af)(1+Af^2)(1+Af^4)
            vf2 A2q = csq(Af), A4q = csq(A2q);
            vf2 one = MKV(1.f, 0.f);
            vf2 S = cmul(one + Af, one + A2q);
            S = cmul(S, one + A4q);
            vf2 G = cmul(S, Bf);
            X[ta] = cmul(X[ta], G);
        }
        dft16<1>(X, v);
        const float sc = 0.015625f;                  // 1/64 fold
        #pragma unroll
        for (int t = 0; t < 16; ++t) {
            vf2 z = v[t] * MKV(sc, sc);
            tre[t][pr][cg] = z.x;
            tim[t][pr][cg] = z.y;
        }
    }
    __syncthreads();
    // inverse H stage 1
    #pragma unroll
    for (int q = 0; q < 2; ++q) {
        int t = ts*2 + q;
        vf2 a[8], Y[8];
        #pragma unroll
        for (int e1 = 0; e1 < 8; ++e1) {
            int pr = LROW(d*8 + e1);
            a[e1] = MKV(tre[t][pr][cl], tim[t][pr][cl]);
        }
        dft8<1>(a, Y);
        #pragma unroll
        for (int h0 = 0; h0 < 8; ++h0) {
            int pr = LROW(d*8 + h0);
            vf2 z = cmul(Y[h0], MKV(twc[h0], -tws[h0]));
            tre[t][pr][cl] = z.x;
            tim[t][pr][cl] = z.y;
        }
    }
    __syncthreads();
    // inverse H stage 2
    #pragma unroll
    for (int q = 0; q < 2; ++q) {
        int t = ts*2 + q;
        vf2 a[8], Y[8];
        #pragma unroll
        for (int e0 = 0; e0 < 8; ++e0) {
            int pr = LROW(e0*8 + d);
            a[e0] = MKV(tre[t][pr][cl], tim[t][pr][cl]);
        }
        dft8<1>(a, Y);
        #pragma unroll
        for (int h1 = 0; h1 < 8; ++h1) {
            int pr = LROW(d + 8*h1);
            tre[t][pr][cl] = Y[h1].x; tim[t][pr][cl] = Y[h1].y;
        }
    }
    __syncthreads();
    for (int i = tid; i < 1024; i += 256) {
        int t = i >> 6, h = i & 63;
        int pr = LROW(h);
        uint4 u;
        __half2 v0 = __float22half2_rn(make_float2(tre[t][pr][0], tim[t][pr][0]));
        __half2 v1 = __float22half2_rn(make_float2(tre[t][pr][1], tim[t][pr][1]));
        __half2 v2 = __float22half2_rn(make_float2(tre[t][pr][2], tim[t][pr][2]));
        __half2 v3 = __float22half2_rn(make_float2(tre[t][pr][3], tim[t][pr][3]));
        u.x = *(unsigned int*)&v0; u.y = *(unsigned int*)&v1;
        u.z = *(unsigned int*)&v2; u.w = *(unsigned int*)&v3;
        g[i] = u;
    }
}

// ------- pass 5: paired inverse real-output W-FFT, fp32 SoA LDS, packed math -------
__global__ __launch_bounds__(256) void p5(const uint4* __restrict__ Z,
                                          float* __restrict__ out) {
    __shared__ float plre[2][64][32];      // 16 KB
    __shared__ float plim[2][64][32];      // 16 KB
    __shared__ float2 tw64[64];
    int bid = blockIdx.x;
    int cq = bid & 3, hq = (bid >> 2) & 15, t = bid >> 6;
    int tid = threadIdx.x;
    if (tid < 64) {
        float s, cw; sincosf(PI2 * tid / 64.0f, &s, &cw);
        tw64[tid] = make_float2(cw, s);
    }
    for (int i = tid; i < 528; i += 256) {               // p(2) x ccl(8) x om(33)
        int p = i & 1, ccl = (i >> 1) & 7, om = i >> 4;
        size_t base = ((size_t)(om*32 + cq*8 + ccl)*16 + t)*64 + hq*4;
        uint4 ua = Z[base + 2*p];
        uint4 ub = Z[base + 2*p + 1];
        const unsigned int* pa = &ua.x;
        const unsigned int* pb = &ub.x;
        #pragma unroll
        for (int j = 0; j < 4; ++j) {
            float2 za = __half22float2(*(const __half2*)&pa[j]);
            float2 zb = __half22float2(*(const __half2*)&pb[j]);
            plre[p][om][ccl*4+j] = za.x - zb.y;
            plim[p][om][ccl*4+j] = za.y + zb.x;
            if (om >= 1 && om <= 31) {
                plre[p][64-om][ccl*4+j] = za.x + zb.y;
                plim[p][64-om][ccl*4+j] = zb.x - za.y;
            }
        }
    }
    __syncthreads();                                          // B1
    int c = tid & 31, s4 = tid >> 5;
    vf2 ar[2][8];
    #pragma unroll
    for (int p = 0; p < 2; ++p)
        #pragma unroll
        for (int h1 = 0; h1 < 8; ++h1)
            ar[p][h1] = MKV(plre[p][h1*8 + s4][c], plim[p][h1*8 + s4][c]);
    __syncthreads();                                          // B2
    #pragma unroll
    for (int p = 0; p < 2; ++p) {
        vf2 Y[8];
        dft8<1>(ar[p], Y);
        #pragma unroll
        for (int k0 = 0; k0 < 8; ++k0) {
            float2 tw = tw64[(s4 * k0) & 63];
            vf2 z = cmul(Y[k0], MKV(tw.x, tw.y));
            plre[p][k0*8 + s4][c] = z.x;
            plim[p][k0*8 + s4][c] = z.y;
        }
    }
    __syncthreads();                                          // B3
    #pragma unroll
    for (int p = 0; p < 2; ++p) {
        vf2 b[8], X[8];
        #pragma unroll
        for (int h0 = 0; h0 < 8; ++h0)
            b[h0] = MKV(plre[p][s4*8 + h0][c], plim[p][s4*8 + h0][c]);
        dft8<1>(b, X);
        float* dst = out + (size_t)(t*64 + hq*4 + 2*p) * 8192 + cq * 32 + c;
        #pragma unroll
        for (int k1 = 0; k1 < 8; ++k1) {
            size_t o = (size_t)(s4 + 8*k1) * 128;
            dst[o]        = X[k1].x * (1.0f / 1024.0f);
            dst[o + 8192] = X[k1].y * (1.0f / 1024.0f);
        }
    }
}

extern "C" void kernel_launch(void* const* d_in, const int* in_sizes, int n_in,
                              void* d_out, int out_size, void* d_ws, size_t ws_size,
                              hipStream_t stream) {
    const float* x  = (const float*)d_in[0];
    const float* Ak = (const float*)d_in[1];
    const float* Bk = (const float*)d_in[2];
    float* out = (float*)d_out;

    // Z: 33*32 chunks x 16 KB = 17.3 MB (uint4-addressed); G tables after.
    uint4* Z = (uint4*)d_ws;
    __half2* Ahw = (__half2*)((char*)d_ws + (size_t)33*32*1024*16);
    __half2* Bhw = Ahw + 3 * 33 * 64 * 128;

    hipLaunchKernelGGL(pA,   dim3(1222), dim3(256), 0, stream, x, Z, Ak, Bk, Ahw, Bhw);
    hipLaunchKernelGGL(pmid, dim3(1056), dim3(256), 0, stream, Z, Ahw, Bhw);
    hipLaunchKernelGGL(p5,   dim3(1024), dim3(256), 0, stream, Z, out);
}